// Round 12
// baseline (453.691 us; speedup 1.0000x reference)
//
#include <hip/hip_runtime.h>
#include <hip/hip_bf16.h>
#include <cstdint>

// ---------------------------------------------------------------------------
// DynamicGAT: GraphConv(2->64) + GAT(64->4x64) + GAT(256->4x64) + GAT(256->64)
// R11: gather256 channel-sliced + XCD-pinned. 8 slices of 32 chans; block b
// owns slice b&7 -> round-robin dispatch pins slice k to XCD k -> each L2
// refills only its 3.2MB slice (row traffic 208->~26MB). Edge weights
// re-hoisted to planar wexpH[head][edge] (bf16) so slices stream 2B/edge.
// ---------------------------------------------------------------------------

typedef __attribute__((ext_vector_type(8))) short bf16x8;
typedef __attribute__((ext_vector_type(4))) float f32x4;

__device__ inline unsigned short f2bf(float f) {
  union { float f; uint32_t u; } x; x.f = f;
  uint32_t r = x.u + 0x7FFF + ((x.u >> 16) & 1);   // RNE
  return (unsigned short)(r >> 16);
}
__device__ inline float bf2f(unsigned short u) {
  union { uint32_t u; float f; } x; x.u = ((uint32_t)u) << 16; return x.f;
}
__device__ inline float lrelu02(float v) { return v > 0.f ? v : 0.2f * v; }

#define CHUNK 2048   // edges per block in bucket passes (8 per thread)

// ---------------- bucket count: LDS histogram, 1 flush atomic per bucket ---
__global__ __launch_bounds__(256) void bcount_kernel(const int* __restrict__ dst,
    int E, int N, int nbk, int* __restrict__ bcount) {
  __shared__ int lh[256];
  int t = threadIdx.x;
  lh[t] = 0;
  __syncthreads();
  int base = blockIdx.x * CHUNK;
  int lim = min(base + CHUNK, E + N);
  for (int i = base + t; i < lim; i += 256) {
    int d = (i < E) ? dst[i] : (i - E);   // self loops appended
    atomicAdd(&lh[d >> 8], 1);
  }
  __syncthreads();
  if (t < nbk && lh[t]) atomicAdd(&bcount[t], lh[t]);
}

// ---------------- bucket scan (196 values, 1 block) ----------------
__global__ void bscan_kernel(const int* __restrict__ bcount, int nbk,
                             int* __restrict__ boffs, int* __restrict__ gcursor,
                             int* __restrict__ rowptr, int N, int total) {
  __shared__ int lds[256];
  int t = threadIdx.x;
  int v = (t < nbk) ? bcount[t] : 0;
  lds[t] = v;
  __syncthreads();
  for (int off = 1; off < 256; off <<= 1) {
    int x = lds[t];
    if (t >= off) x += lds[t - off];
    __syncthreads();
    lds[t] = x;
    __syncthreads();
  }
  if (t < nbk) {
    int ex = lds[t] - v;
    boffs[t] = ex;
    gcursor[t] = ex;
  }
  if (t == 0) {
    boffs[nbk] = total;
    rowptr[0] = 0;
    rowptr[N] = total;
  }
}

// ---------------- bucket scatter: pairs into bucket-sorted array -----------
__global__ __launch_bounds__(256) void bscatter_kernel(const int* __restrict__ src,
    const int* __restrict__ dst, int E, int N, int nbk,
    int* __restrict__ gcursor, int2* __restrict__ pairs) {
  __shared__ int lh[256];
  __shared__ int gb[256];
  int t = threadIdx.x;
  lh[t] = 0;
  __syncthreads();
  int base = blockIdx.x * CHUNK;
  int lim = min(base + CHUNK, E + N);
  int myS[8], myD[8], myR[8];
#pragma unroll
  for (int u = 0; u < 8; ++u) {
    int i = base + t + u * 256;
    myD[u] = -1;
    if (i < lim) {
      int s, d;
      if (i < E) { s = src[i]; d = dst[i]; }
      else       { s = i - E; d = s; }
      myS[u] = s; myD[u] = d;
      myR[u] = atomicAdd(&lh[d >> 8], 1);
    }
  }
  __syncthreads();
  if (t < nbk && lh[t]) gb[t] = atomicAdd(&gcursor[t], lh[t]);
  __syncthreads();
#pragma unroll
  for (int u = 0; u < 8; ++u) {
    if (myD[u] >= 0) {
      int b = myD[u] >> 8;
      pairs[gb[b] + myR[u]] = make_int2(myS[u], myD[u]);
    }
  }
}

// ---------------- per-bucket CSR finalize: rowptr slice + adj --------------
__global__ __launch_bounds__(256) void bcsr_kernel(const int2* __restrict__ pairs,
    const int* __restrict__ boffs, int nbk, int N,
    int* __restrict__ rowptr, int* __restrict__ adj) {
  __shared__ int lc[256];
  __shared__ int sc[256];
  int b = blockIdx.x;
  int t = threadIdx.x;
  int p0 = boffs[b], p1 = boffs[b + 1];
  lc[t] = 0;
  __syncthreads();
  for (int i = p0 + t; i < p1; i += 256)
    atomicAdd(&lc[pairs[i].y & 255], 1);
  __syncthreads();
  int v = lc[t];
  sc[t] = v;
  __syncthreads();
  for (int off = 1; off < 256; off <<= 1) {
    int x = sc[t];
    if (t >= off) x += sc[t - off];
    __syncthreads();
    sc[t] = x;
    __syncthreads();
  }
  int node = (b << 8) + t;
  if (node < N) rowptr[node + 1] = p0 + sc[t];
  lc[t] = p0 + sc[t] - v;   // cursor = exclusive
  __syncthreads();
  for (int i = p0 + t; i < p1; i += 256) {
    int2 pr = pairs[i];
    int slot = atomicAdd(&lc[pr.y & 255], 1);
    adj[slot] = pr.x;
  }
}

// ---------------- GraphConv via CSR gather (fused) ----------------
__global__ __launch_bounds__(256) void graphconv_csr(const float* __restrict__ x,
    const int* __restrict__ rowptr, const int* __restrict__ adj,
    const float* __restrict__ W_rel, const float* __restrict__ b_rel,
    const float* __restrict__ W_root, unsigned short* __restrict__ h0b, int N) {
  int w = threadIdx.x >> 6, l = threadIdx.x & 63;
  int node = blockIdx.x * 4 + w;
  if (node >= N) return;
  int s0 = rowptr[node], s1 = rowptr[node + 1];
  float a0 = 0.f, a1 = 0.f;
  for (int s = s0 + l; s < s1; s += 64) {
    int j = adj[s];
    float2 xv = *reinterpret_cast<const float2*>(x + (size_t)j * 2);
    a0 += xv.x; a1 += xv.y;
  }
#pragma unroll
  for (int off = 1; off < 64; off <<= 1) {
    a0 += __shfl_xor(a0, off);
    a1 += __shfl_xor(a1, off);
  }
  float2 xi = *reinterpret_cast<const float2*>(x + (size_t)node * 2);
  a0 -= xi.x; a1 -= xi.y;   // remove appended self loop (GraphConv: real edges)
  int c = l;
  float v = a0 * W_rel[c] + a1 * W_rel[64 + c]
          + xi.x * W_root[c] + xi.y * W_root[64 + c] + b_rel[c];
  h0b[(size_t)node * 64 + c] = f2bf(fmaxf(v, 0.f));
}

// ---------------- weight transpose+convert (all 3), W[K][N] -> Wt[N][K] ----
__global__ void wt3_kernel(const float* __restrict__ W1, unsigned short* __restrict__ Wt1,
                           const float* __restrict__ W2, unsigned short* __restrict__ Wt2,
                           const float* __restrict__ W3, unsigned short* __restrict__ Wt3) {
  int i = blockIdx.x * blockDim.x + threadIdx.x;
  if (i < 16384) {                    // W1: K=64, N=256
    int n = i >> 6, k = i & 63;
    Wt1[i] = f2bf(W1[k * 256 + n]);
  } else if (i < 16384 + 65536) {     // W2: K=256, N=256
    int j = i - 16384;
    int n = j >> 8, k = j & 255;
    Wt2[j] = f2bf(W2[k * 256 + n]);
  } else if (i < 16384 + 65536 + 16384) {  // W3: K=256, N=64
    int j = i - 16384 - 65536;
    int n = j >> 8, k = j & 255;
    Wt3[j] = f2bf(W3[k * 64 + n]);
  }
}

// ---------------- bf16 MFMA GEMM + fused attention logits ------------------
template <int BM, int BN, int WARPS_M, int WARPS_N, int H>
__global__ __launch_bounds__(256) void mfma_gemm(const unsigned short* __restrict__ A,
    const unsigned short* __restrict__ Bt, unsigned short* __restrict__ C,
    const float* __restrict__ a_s, const float* __restrict__ a_d,
    float* __restrict__ alS, float* __restrict__ alD, int M, int N, int K) {
  __shared__ unsigned char lds[(BM + BN) * 80];
  unsigned char* As = lds;
  unsigned char* Bs = lds + BM * 80;
  int t = threadIdx.x;
  int w = t >> 6, l = t & 63;
  int wm = w / WARPS_N, wn = w % WARPS_N;
  int row0 = blockIdx.y * BM;
  int col0 = blockIdx.x * BN;
  f32x4 acc[4][4] = {};
  int slot = l >> 4, rr = l & 15;
  for (int k0 = 0; k0 < K; k0 += 32) {
    if (k0) __syncthreads();
#pragma unroll
    for (int u = 0; u < BM * 4 / 256; ++u) {
      int s = t + u * 256;
      int r = s >> 2, sl = s & 3;
      int gr = row0 + r;
      uint4 v = make_uint4(0u, 0u, 0u, 0u);
      if (gr < M) v = *reinterpret_cast<const uint4*>(A + (size_t)gr * K + k0 + sl * 8);
      *reinterpret_cast<uint4*>(As + r * 80 + sl * 16) = v;
    }
#pragma unroll
    for (int u = 0; u < BN * 4 / 256; ++u) {
      int s = t + u * 256;
      int r = s >> 2, sl = s & 3;
      uint4 v = *reinterpret_cast<const uint4*>(Bt + (size_t)(col0 + r) * K + k0 + sl * 8);
      *reinterpret_cast<uint4*>(Bs + r * 80 + sl * 16) = v;
    }
    __syncthreads();
    bf16x8 a[4], b[4];
#pragma unroll
    for (int i = 0; i < 4; ++i)
      a[i] = *reinterpret_cast<const bf16x8*>(As + (wm * 64 + i * 16 + rr) * 80 + slot * 16);
#pragma unroll
    for (int j = 0; j < 4; ++j)
      b[j] = *reinterpret_cast<const bf16x8*>(Bs + (wn * 64 + j * 16 + rr) * 80 + slot * 16);
#pragma unroll
    for (int i = 0; i < 4; ++i)
#pragma unroll
      for (int j = 0; j < 4; ++j)
        acc[i][j] = __builtin_amdgcn_mfma_f32_16x16x32_bf16(a[i], b[j], acc[i][j], 0, 0, 0);
  }
  // C write. C/D layout: col = l&15, row = (l>>4)*4 + reg
  int rb = row0 + wm * 64 + (l >> 4) * 4;
  int cb = col0 + wn * 64 + (l & 15);
#pragma unroll
  for (int i = 0; i < 4; ++i) {
#pragma unroll
    for (int r = 0; r < 4; ++r) {
      int gr = rb + i * 16 + r;
      if (gr < M) {
#pragma unroll
        for (int j = 0; j < 4; ++j)
          C[(size_t)gr * N + cb + j * 16] = f2bf(acc[i][j][r]);
      }
    }
  }
  // fused logits: this warp's head
  int hd = (col0 >> 6) + wn;
  int ch = l & 15;
  float as0 = a_s[hd * 64 + ch], as1 = a_s[hd * 64 + ch + 16];
  float as2 = a_s[hd * 64 + ch + 32], as3 = a_s[hd * 64 + ch + 48];
  float ad0 = a_d[hd * 64 + ch], ad1 = a_d[hd * 64 + ch + 16];
  float ad2 = a_d[hd * 64 + ch + 32], ad3 = a_d[hd * 64 + ch + 48];
#pragma unroll
  for (int i = 0; i < 4; ++i) {
#pragma unroll
    for (int r = 0; r < 4; ++r) {
      float ps = acc[i][0][r] * as0 + acc[i][1][r] * as1
               + acc[i][2][r] * as2 + acc[i][3][r] * as3;
      float pd = acc[i][0][r] * ad0 + acc[i][1][r] * ad1
               + acc[i][2][r] * ad2 + acc[i][3][r] * ad3;
#pragma unroll
      for (int off = 1; off < 16; off <<= 1) {
        ps += __shfl_xor(ps, off);
        pd += __shfl_xor(pd, off);
      }
      if ((l & 15) == 0) {
        int gr = rb + i * 16 + r;
        if (gr < M) {
          alS[gr * H + hd] = ps;
          alD[gr * H + hd] = pd;
        }
      }
    }
  }
}

// ---------------- edge weights, 4 heads, planar [head][edge] bf16 ----------
__global__ __launch_bounds__(256) void edgew4_kernel(const float4* __restrict__ alS4,
    const float4* __restrict__ alD4, const int* __restrict__ rowptr,
    const int* __restrict__ adj, unsigned short* __restrict__ wexpH,
    int N, int ESL) {
  int w = threadIdx.x >> 6, l = threadIdx.x & 63;
  int node = blockIdx.x * 4 + w;
  if (node >= N) return;
  float4 ad = alD4[node];
  int s0 = rowptr[node], s1 = rowptr[node + 1];
  for (int s = s0 + l; s < s1; s += 64) {
    int j = adj[s];
    float4 as = alS4[j];
    wexpH[0 * (size_t)ESL + s] = f2bf(__expf(lrelu02(as.x + ad.x)));
    wexpH[1 * (size_t)ESL + s] = f2bf(__expf(lrelu02(as.y + ad.y)));
    wexpH[2 * (size_t)ESL + s] = f2bf(__expf(lrelu02(as.z + ad.z)));
    wexpH[3 * (size_t)ESL + s] = f2bf(__expf(lrelu02(as.w + ad.w)));
  }
}

// ---------------- GAT gather 256ch, channel-sliced + XCD-pinned ------------
// block b: slice = b&7 (32 chans, 64B) -> round-robin dispatch pins slice k
// to XCD k. Wave = 8 edge-slots x 8 lanes (4 chans each); slot-strided edges;
// slot reduce via shfl_xor(8,16,32). 16 nodes per block (4 per wave).
template <bool RELU>
__global__ __launch_bounds__(256) void gat_g256s(const unsigned short* __restrict__ hW,
    const unsigned short* __restrict__ wexpH,
    const int* __restrict__ rowptr, const int* __restrict__ adj,
    const float* __restrict__ bias, unsigned short* __restrict__ outb,
    int N, int ESL) {
  int slice = blockIdx.x & 7;
  int ng = blockIdx.x >> 3;
  int w = threadIdx.x >> 6, l = threadIdx.x & 63;
  int slot = l >> 3;            // edge slot 0..7
  int q = l & 7;                // chan quad within slice
  int cbase = slice * 32 + q * 4;
  const unsigned short* wplane = wexpH + (size_t)(slice >> 1) * ESL;
  float b0 = bias[cbase + 0], b1 = bias[cbase + 1];
  float b2 = bias[cbase + 2], b3 = bias[cbase + 3];
#pragma unroll
  for (int k = 0; k < 4; ++k) {
    int node = ng * 16 + w * 4 + k;
    if (node < N) {
      int s0 = rowptr[node], s1 = rowptr[node + 1];
      float den = 0.f, a0 = 0.f, a1 = 0.f, a2 = 0.f, a3 = 0.f;
      for (int e = s0 + slot; e < s1; e += 8) {
        int idx = adj[e];
        float wt = bf2f(wplane[e]);
        ushort4 hv = *reinterpret_cast<const ushort4*>(hW + (size_t)idx * 256 + cbase);
        den += wt;
        a0 += wt * bf2f(hv.x);
        a1 += wt * bf2f(hv.y);
        a2 += wt * bf2f(hv.z);
        a3 += wt * bf2f(hv.w);
      }
#pragma unroll
      for (int off = 8; off <= 32; off <<= 1) {
        den += __shfl_xor(den, off);
        a0 += __shfl_xor(a0, off);
        a1 += __shfl_xor(a1, off);
        a2 += __shfl_xor(a2, off);
        a3 += __shfl_xor(a3, off);
      }
      if (slot == 0) {
        float inv = 1.f / (den + 1e-16f);
        float o0 = a0 * inv + b0;
        float o1 = a1 * inv + b1;
        float o2 = a2 * inv + b2;
        float o3 = a3 * inv + b3;
        if (RELU) {
          o0 = fmaxf(o0, 0.f); o1 = fmaxf(o1, 0.f);
          o2 = fmaxf(o2, 0.f); o3 = fmaxf(o3, 0.f);
        }
        ushort4 ov;
        ov.x = f2bf(o0); ov.y = f2bf(o1); ov.z = f2bf(o2); ov.w = f2bf(o3);
        *reinterpret_cast<ushort4*>(outb + (size_t)node * 256 + cbase) = ov;
      }
    }
  }
}

// ---------------- GAT gather, 64 ch (1 head), bf16 in, fp32 out ------------
template <bool RELU>
__global__ __launch_bounds__(256) void gat_gather64(const unsigned short* __restrict__ hW,
    const float* __restrict__ alS, const float* __restrict__ alD,
    const int* __restrict__ rowptr, const int* __restrict__ adj,
    const float* __restrict__ bias, float* __restrict__ out, int N) {
  int w = threadIdx.x >> 6, l = threadIdx.x & 63;
  int node = blockIdx.x * 4 + w;
  if (node >= N) return;
  int g = l >> 4;
  int c = (l & 15) << 2;
  float ald = alD[node];
  int s0 = rowptr[node], s1 = rowptr[node + 1];
  float den = 0.f, a0 = 0.f, a1 = 0.f, a2 = 0.f, a3 = 0.f;
  int s = s0 + g;
  for (; s + 12 < s1; s += 16) {
    int ix[4];
    ix[0] = adj[s]; ix[1] = adj[s + 4]; ix[2] = adj[s + 8]; ix[3] = adj[s + 12];
    float vv[4];
#pragma unroll
    for (int u = 0; u < 4; ++u) vv[u] = alS[ix[u]];
    ushort4 hh[4];
#pragma unroll
    for (int u = 0; u < 4; ++u)
      hh[u] = *reinterpret_cast<const ushort4*>(hW + (size_t)ix[u] * 64 + c);
#pragma unroll
    for (int u = 0; u < 4; ++u) {
      float wt = __expf(lrelu02(vv[u] + ald));
      den += wt;
      a0 += wt * bf2f(hh[u].x);
      a1 += wt * bf2f(hh[u].y);
      a2 += wt * bf2f(hh[u].z);
      a3 += wt * bf2f(hh[u].w);
    }
  }
  for (; s < s1; s += 4) {
    int i0 = adj[s];
    float v0 = alS[i0];
    ushort4 h0 = *reinterpret_cast<const ushort4*>(hW + (size_t)i0 * 64 + c);
    float w0 = __expf(lrelu02(v0 + ald));
    den += w0;
    a0 += w0 * bf2f(h0.x);
    a1 += w0 * bf2f(h0.y);
    a2 += w0 * bf2f(h0.z);
    a3 += w0 * bf2f(h0.w);
  }
#pragma unroll
  for (int off = 16; off <= 32; off <<= 1) {
    den += __shfl_xor(den, off);
    a0 += __shfl_xor(a0, off);
    a1 += __shfl_xor(a1, off);
    a2 += __shfl_xor(a2, off);
    a3 += __shfl_xor(a3, off);
  }
  if (g == 0) {
    float inv = 1.f / (den + 1e-16f);
    float o0 = a0 * inv + bias[c + 0];
    float o1 = a1 * inv + bias[c + 1];
    float o2 = a2 * inv + bias[c + 2];
    float o3 = a3 * inv + bias[c + 3];
    if (RELU) {
      o0 = fmaxf(o0, 0.f); o1 = fmaxf(o1, 0.f);
      o2 = fmaxf(o2, 0.f); o3 = fmaxf(o3, 0.f);
    }
    *reinterpret_cast<float4*>(out + (size_t)node * 64 + c) = make_float4(o0, o1, o2, o3);
  }
}

// ---------------------------------------------------------------------------
extern "C" void kernel_launch(void* const* d_in, const int* in_sizes, int n_in,
                              void* d_out, int out_size, void* d_ws, size_t ws_size,
                              hipStream_t stream) {
  const float* x      = (const float*)d_in[0];
  const float* W_rel  = (const float*)d_in[1];
  const float* b_rel  = (const float*)d_in[2];
  const float* W_root = (const float*)d_in[3];
  const float* W1     = (const float*)d_in[4];
  const float* a_s1   = (const float*)d_in[5];
  const float* a_d1   = (const float*)d_in[6];
  const float* b1     = (const float*)d_in[7];
  const float* W2     = (const float*)d_in[8];
  const float* a_s2   = (const float*)d_in[9];
  const float* a_d2   = (const float*)d_in[10];
  const float* b2     = (const float*)d_in[11];
  const float* W3     = (const float*)d_in[12];
  const float* a_s3   = (const float*)d_in[13];
  const float* a_d3   = (const float*)d_in[14];
  const float* b3     = (const float*)d_in[15];
  const int*   ei     = (const int*)d_in[16];

  int N = in_sizes[0] / 2;
  int E = in_sizes[16] / 2;
  const int* srcp = ei;
  const int* dstp = ei + E;
  int ESL = E + N;
  int nbk = (N + 255) >> 8;   // 196 buckets of 256 dst nodes

  // workspace layout (~89 MB), 16B-aligned sections
  unsigned short* h0b   = (unsigned short*)d_ws;           // N*64 bf16
  unsigned short* bufX  = h0b + (size_t)N * 64;            // N*256 bf16
  unsigned short* bufY  = bufX + (size_t)N * 256;          // N*256 bf16
  unsigned short* bufZ  = bufY + (size_t)N * 256;          // N*64 bf16
  unsigned short* Wt1   = bufZ + (size_t)N * 64;           // 256*64
  unsigned short* Wt2   = Wt1 + 256 * 64;                  // 256*256
  unsigned short* Wt3   = Wt2 + 256 * 256;                 // 64*256
  unsigned short* wexpH = Wt3 + 64 * 256;                  // 4*ESL bf16 planar
  float* alS  = (float*)(wexpH + (size_t)4 * ESL);         // N*4
  float* alD  = alS + (size_t)N * 4;                       // N*4
  int2* pairs = (int2*)(alD + (size_t)N * 4);              // ESL int2
  int* adj    = (int*)(pairs + ESL);                       // ESL
  int* rowptr = adj + ESL;                                 // N+1
  int* bcount = rowptr + (N + 1);                          // nbk
  int* boffs  = bcount + 256;                              // nbk+1
  int* gcursor= boffs + 257;                               // nbk

  hipMemsetAsync(bcount, 0, 256 * sizeof(int), stream);

  int tb = 256;
  int nch = (ESL + CHUNK - 1) / CHUNK;
  int gN4 = (N + 3) / 4;
  int gSl = 8 * ((N + 15) / 16);   // sliced gather grid

  // bucket-local CSR build (shared by GraphConv + all 3 GAT layers)
  bcount_kernel<<<nch, tb, 0, stream>>>(dstp, E, N, nbk, bcount);
  bscan_kernel<<<1, 256, 0, stream>>>(bcount, nbk, boffs, gcursor, rowptr, N, ESL);
  bscatter_kernel<<<nch, tb, 0, stream>>>(srcp, dstp, E, N, nbk, gcursor, pairs);
  bcsr_kernel<<<nbk, tb, 0, stream>>>(pairs, boffs, nbk, N, rowptr, adj);

  // weight transpose/convert (single launch)
  wt3_kernel<<<(98304 + tb - 1) / tb, tb, 0, stream>>>(W1, Wt1, W2, Wt2, W3, Wt3);

  // GraphConv via CSR gather (self-loop subtracted) + ReLU -> bf16
  graphconv_csr<<<gN4, 256, 0, stream>>>(x, rowptr, adj, W_rel, b_rel, W_root, h0b, N);

  dim3 gA(256 / 128, (N + 127) / 128);   // layers 1,2: N=256 -> 2 col tiles
  dim3 gB(1, (N + 255) / 256);           // layer 3: N=64

  // GAT layer 1: 64 -> 4x64, relu
  mfma_gemm<128, 128, 2, 2, 4><<<gA, 256, 0, stream>>>(h0b, Wt1, bufX, a_s1, a_d1, alS, alD, N, 256, 64);
  edgew4_kernel<<<gN4, 256, 0, stream>>>((const float4*)alS, (const float4*)alD, rowptr, adj, wexpH, N, ESL);
  gat_g256s<true><<<gSl, 256, 0, stream>>>(bufX, wexpH, rowptr, adj, b1, bufY, N, ESL);

  // GAT layer 2: 256 -> 4x64, relu
  mfma_gemm<128, 128, 2, 2, 4><<<gA, 256, 0, stream>>>(bufY, Wt2, bufX, a_s2, a_d2, alS, alD, N, 256, 256);
  edgew4_kernel<<<gN4, 256, 0, stream>>>((const float4*)alS, (const float4*)alD, rowptr, adj, wexpH, N, ESL);
  gat_g256s<true><<<gSl, 256, 0, stream>>>(bufX, wexpH, rowptr, adj, b2, bufY, N, ESL);

  // GAT layer 3: 256 -> 64, heads=1, no relu
  mfma_gemm<256, 64, 4, 1, 1><<<gB, 256, 0, stream>>>(bufY, Wt3, bufZ, a_s3, a_d3, alS, alD, N, 64, 256);
  gat_gather64<false><<<gN4, 256, 0, stream>>>(bufZ, alS, alD, rowptr, adj, b3, (float*)d_out, N);
}

// Round 13
// 288.868 us; speedup vs baseline: 1.5706x; 1.5706x over previous
//
#include <hip/hip_runtime.h>
#include <hip/hip_bf16.h>
#include <cstdint>

// ---------------------------------------------------------------------------
// DynamicGAT: GraphConv(2->64) + GAT(64->4x64) + GAT(256->4x64) + GAT(256->64)
// R12: revert to R10/R11 best (channel-slicing regressed: XCD pinning didn't
// hold + channel hotspotting). Micro-opts: pairs packed to u32 (src:16b,
// dst&255:8b), bcount zeroing folded into wt3 (one fewer launch).
// gather256 floor (~66us) confirmed structural: 208MB/XCD-refill @ 3.6TB/s.
// ---------------------------------------------------------------------------

typedef __attribute__((ext_vector_type(8))) short bf16x8;
typedef __attribute__((ext_vector_type(4))) float f32x4;

__device__ inline unsigned short f2bf(float f) {
  union { float f; uint32_t u; } x; x.f = f;
  uint32_t r = x.u + 0x7FFF + ((x.u >> 16) & 1);   // RNE
  return (unsigned short)(r >> 16);
}
__device__ inline float bf2f(unsigned short u) {
  union { uint32_t u; float f; } x; x.u = ((uint32_t)u) << 16; return x.f;
}
__device__ inline float lrelu02(float v) { return v > 0.f ? v : 0.2f * v; }

#define CHUNK 2048   // edges per block in bucket passes (8 per thread)

// ---------------- bucket count: LDS histogram, 1 flush atomic per bucket ---
__global__ __launch_bounds__(256) void bcount_kernel(const int* __restrict__ dst,
    int E, int N, int nbk, int* __restrict__ bcount) {
  __shared__ int lh[256];
  int t = threadIdx.x;
  lh[t] = 0;
  __syncthreads();
  int base = blockIdx.x * CHUNK;
  int lim = min(base + CHUNK, E + N);
  for (int i = base + t; i < lim; i += 256) {
    int d = (i < E) ? dst[i] : (i - E);   // self loops appended
    atomicAdd(&lh[d >> 8], 1);
  }
  __syncthreads();
  if (t < nbk && lh[t]) atomicAdd(&bcount[t], lh[t]);
}

// ---------------- bucket scan (196 values, 1 block) ----------------
__global__ void bscan_kernel(const int* __restrict__ bcount, int nbk,
                             int* __restrict__ boffs, int* __restrict__ gcursor,
                             int* __restrict__ rowptr, int N, int total) {
  __shared__ int lds[256];
  int t = threadIdx.x;
  int v = (t < nbk) ? bcount[t] : 0;
  lds[t] = v;
  __syncthreads();
  for (int off = 1; off < 256; off <<= 1) {
    int x = lds[t];
    if (t >= off) x += lds[t - off];
    __syncthreads();
    lds[t] = x;
    __syncthreads();
  }
  if (t < nbk) {
    int ex = lds[t] - v;
    boffs[t] = ex;
    gcursor[t] = ex;
  }
  if (t == 0) {
    boffs[nbk] = total;
    rowptr[0] = 0;
    rowptr[N] = total;
  }
}

// ---------------- bucket scatter: packed (src | (dst&255)<<16) -------------
// src < 65536 (N=50000) so it fits in 16 bits; dst low byte identifies the
// node within its bucket. Halves pair traffic vs int2.
__global__ __launch_bounds__(256) void bscatter_kernel(const int* __restrict__ src,
    const int* __restrict__ dst, int E, int N, int nbk,
    int* __restrict__ gcursor, uint32_t* __restrict__ pairs) {
  __shared__ int lh[256];
  __shared__ int gb[256];
  int t = threadIdx.x;
  lh[t] = 0;
  __syncthreads();
  int base = blockIdx.x * CHUNK;
  int lim = min(base + CHUNK, E + N);
  int myS[8], myD[8], myR[8];
#pragma unroll
  for (int u = 0; u < 8; ++u) {
    int i = base + t + u * 256;
    myD[u] = -1;
    if (i < lim) {
      int s, d;
      if (i < E) { s = src[i]; d = dst[i]; }
      else       { s = i - E; d = s; }
      myS[u] = s; myD[u] = d;
      myR[u] = atomicAdd(&lh[d >> 8], 1);
    }
  }
  __syncthreads();
  if (t < nbk && lh[t]) gb[t] = atomicAdd(&gcursor[t], lh[t]);
  __syncthreads();
#pragma unroll
  for (int u = 0; u < 8; ++u) {
    if (myD[u] >= 0) {
      int b = myD[u] >> 8;
      pairs[gb[b] + myR[u]] = (uint32_t)myS[u] | ((uint32_t)(myD[u] & 255) << 16);
    }
  }
}

// ---------------- per-bucket CSR finalize: rowptr slice + adj --------------
__global__ __launch_bounds__(256) void bcsr_kernel(const uint32_t* __restrict__ pairs,
    const int* __restrict__ boffs, int nbk, int N,
    int* __restrict__ rowptr, int* __restrict__ adj) {
  __shared__ int lc[256];
  __shared__ int sc[256];
  int b = blockIdx.x;
  int t = threadIdx.x;
  int p0 = boffs[b], p1 = boffs[b + 1];
  lc[t] = 0;
  __syncthreads();
  for (int i = p0 + t; i < p1; i += 256)
    atomicAdd(&lc[(pairs[i] >> 16) & 255], 1);
  __syncthreads();
  int v = lc[t];
  sc[t] = v;
  __syncthreads();
  for (int off = 1; off < 256; off <<= 1) {
    int x = sc[t];
    if (t >= off) x += sc[t - off];
    __syncthreads();
    sc[t] = x;
    __syncthreads();
  }
  int node = (b << 8) + t;
  if (node < N) rowptr[node + 1] = p0 + sc[t];
  lc[t] = p0 + sc[t] - v;   // cursor = exclusive
  __syncthreads();
  for (int i = p0 + t; i < p1; i += 256) {
    uint32_t pr = pairs[i];
    int slot = atomicAdd(&lc[(pr >> 16) & 255], 1);
    adj[slot] = (int)(pr & 0xFFFFu);
  }
}

// ---------------- GraphConv via CSR gather (fused) ----------------
__global__ __launch_bounds__(256) void graphconv_csr(const float* __restrict__ x,
    const int* __restrict__ rowptr, const int* __restrict__ adj,
    const float* __restrict__ W_rel, const float* __restrict__ b_rel,
    const float* __restrict__ W_root, unsigned short* __restrict__ h0b, int N) {
  int w = threadIdx.x >> 6, l = threadIdx.x & 63;
  int node = blockIdx.x * 4 + w;
  if (node >= N) return;
  int s0 = rowptr[node], s1 = rowptr[node + 1];
  float a0 = 0.f, a1 = 0.f;
  for (int s = s0 + l; s < s1; s += 64) {
    int j = adj[s];
    float2 xv = *reinterpret_cast<const float2*>(x + (size_t)j * 2);
    a0 += xv.x; a1 += xv.y;
  }
#pragma unroll
  for (int off = 1; off < 64; off <<= 1) {
    a0 += __shfl_xor(a0, off);
    a1 += __shfl_xor(a1, off);
  }
  float2 xi = *reinterpret_cast<const float2*>(x + (size_t)node * 2);
  a0 -= xi.x; a1 -= xi.y;   // remove appended self loop (GraphConv: real edges)
  int c = l;
  float v = a0 * W_rel[c] + a1 * W_rel[64 + c]
          + xi.x * W_root[c] + xi.y * W_root[64 + c] + b_rel[c];
  h0b[(size_t)node * 64 + c] = f2bf(fmaxf(v, 0.f));
}

// ---------------- weight transpose+convert (all 3) + bcount zero -----------
__global__ void wt3_kernel(const float* __restrict__ W1, unsigned short* __restrict__ Wt1,
                           const float* __restrict__ W2, unsigned short* __restrict__ Wt2,
                           const float* __restrict__ W3, unsigned short* __restrict__ Wt3,
                           int* __restrict__ bcount) {
  int i = blockIdx.x * blockDim.x + threadIdx.x;
  if (blockIdx.x == 0) bcount[threadIdx.x] = 0;   // replaces memset launch
  if (i < 16384) {                    // W1: K=64, N=256
    int n = i >> 6, k = i & 63;
    Wt1[i] = f2bf(W1[k * 256 + n]);
  } else if (i < 16384 + 65536) {     // W2: K=256, N=256
    int j = i - 16384;
    int n = j >> 8, k = j & 255;
    Wt2[j] = f2bf(W2[k * 256 + n]);
  } else if (i < 16384 + 65536 + 16384) {  // W3: K=256, N=64
    int j = i - 16384 - 65536;
    int n = j >> 8, k = j & 255;
    Wt3[j] = f2bf(W3[k * 64 + n]);
  }
}

// ---------------- bf16 MFMA GEMM + fused attention logits ------------------
template <int BM, int BN, int WARPS_M, int WARPS_N, int H>
__global__ __launch_bounds__(256) void mfma_gemm(const unsigned short* __restrict__ A,
    const unsigned short* __restrict__ Bt, unsigned short* __restrict__ C,
    const float* __restrict__ a_s, const float* __restrict__ a_d,
    float* __restrict__ alS, float* __restrict__ alD, int M, int N, int K) {
  __shared__ unsigned char lds[(BM + BN) * 80];
  unsigned char* As = lds;
  unsigned char* Bs = lds + BM * 80;
  int t = threadIdx.x;
  int w = t >> 6, l = t & 63;
  int wm = w / WARPS_N, wn = w % WARPS_N;
  int row0 = blockIdx.y * BM;
  int col0 = blockIdx.x * BN;
  f32x4 acc[4][4] = {};
  int slot = l >> 4, rr = l & 15;
  for (int k0 = 0; k0 < K; k0 += 32) {
    if (k0) __syncthreads();
#pragma unroll
    for (int u = 0; u < BM * 4 / 256; ++u) {
      int s = t + u * 256;
      int r = s >> 2, sl = s & 3;
      int gr = row0 + r;
      uint4 v = make_uint4(0u, 0u, 0u, 0u);
      if (gr < M) v = *reinterpret_cast<const uint4*>(A + (size_t)gr * K + k0 + sl * 8);
      *reinterpret_cast<uint4*>(As + r * 80 + sl * 16) = v;
    }
#pragma unroll
    for (int u = 0; u < BN * 4 / 256; ++u) {
      int s = t + u * 256;
      int r = s >> 2, sl = s & 3;
      uint4 v = *reinterpret_cast<const uint4*>(Bt + (size_t)(col0 + r) * K + k0 + sl * 8);
      *reinterpret_cast<uint4*>(Bs + r * 80 + sl * 16) = v;
    }
    __syncthreads();
    bf16x8 a[4], b[4];
#pragma unroll
    for (int i = 0; i < 4; ++i)
      a[i] = *reinterpret_cast<const bf16x8*>(As + (wm * 64 + i * 16 + rr) * 80 + slot * 16);
#pragma unroll
    for (int j = 0; j < 4; ++j)
      b[j] = *reinterpret_cast<const bf16x8*>(Bs + (wn * 64 + j * 16 + rr) * 80 + slot * 16);
#pragma unroll
    for (int i = 0; i < 4; ++i)
#pragma unroll
      for (int j = 0; j < 4; ++j)
        acc[i][j] = __builtin_amdgcn_mfma_f32_16x16x32_bf16(a[i], b[j], acc[i][j], 0, 0, 0);
  }
  // C write. C/D layout: col = l&15, row = (l>>4)*4 + reg
  int rb = row0 + wm * 64 + (l >> 4) * 4;
  int cb = col0 + wn * 64 + (l & 15);
#pragma unroll
  for (int i = 0; i < 4; ++i) {
#pragma unroll
    for (int r = 0; r < 4; ++r) {
      int gr = rb + i * 16 + r;
      if (gr < M) {
#pragma unroll
        for (int j = 0; j < 4; ++j)
          C[(size_t)gr * N + cb + j * 16] = f2bf(acc[i][j][r]);
      }
    }
  }
  // fused logits: this warp's head
  int hd = (col0 >> 6) + wn;
  int ch = l & 15;
  float as0 = a_s[hd * 64 + ch], as1 = a_s[hd * 64 + ch + 16];
  float as2 = a_s[hd * 64 + ch + 32], as3 = a_s[hd * 64 + ch + 48];
  float ad0 = a_d[hd * 64 + ch], ad1 = a_d[hd * 64 + ch + 16];
  float ad2 = a_d[hd * 64 + ch + 32], ad3 = a_d[hd * 64 + ch + 48];
#pragma unroll
  for (int i = 0; i < 4; ++i) {
#pragma unroll
    for (int r = 0; r < 4; ++r) {
      float ps = acc[i][0][r] * as0 + acc[i][1][r] * as1
               + acc[i][2][r] * as2 + acc[i][3][r] * as3;
      float pd = acc[i][0][r] * ad0 + acc[i][1][r] * ad1
               + acc[i][2][r] * ad2 + acc[i][3][r] * ad3;
#pragma unroll
      for (int off = 1; off < 16; off <<= 1) {
        ps += __shfl_xor(ps, off);
        pd += __shfl_xor(pd, off);
      }
      if ((l & 15) == 0) {
        int gr = rb + i * 16 + r;
        if (gr < M) {
          alS[gr * H + hd] = ps;
          alD[gr * H + hd] = pd;
        }
      }
    }
  }
}

// ---------------- GAT gather, 256 ch (4 heads), bf16 in/out ----------------
// wave per node; lane l covers channels [4l,4l+4), head=l>>4. Inline max-free
// softmax weights. 8x edge unroll: 16 row loads in flight per wave.
template <bool RELU>
__global__ __launch_bounds__(256) void gat_gather256(const unsigned short* __restrict__ hW,
    const float* __restrict__ alS, const float* __restrict__ alD,
    const int* __restrict__ rowptr, const int* __restrict__ adj,
    const float* __restrict__ bias, unsigned short* __restrict__ outb, int N) {
  int w = threadIdx.x >> 6, l = threadIdx.x & 63;
  int node = blockIdx.x * 4 + w;
  if (node >= N) return;
  int head = l >> 4;
  int c = l << 2;
  float ald = alD[node * 4 + head];
  int s0 = rowptr[node], s1 = rowptr[node + 1];
  float den = 0.f, a0 = 0.f, a1 = 0.f, a2 = 0.f, a3 = 0.f;
  int s = s0;
  for (; s + 8 <= s1; s += 8) {
    int ix[8];
#pragma unroll
    for (int u = 0; u < 8; ++u) ix[u] = adj[s + u];
    float vv[8];
#pragma unroll
    for (int u = 0; u < 8; ++u) vv[u] = alS[ix[u] * 4 + head];
    ushort4 hh[8];
#pragma unroll
    for (int u = 0; u < 8; ++u)
      hh[u] = *reinterpret_cast<const ushort4*>(hW + (size_t)ix[u] * 256 + c);
    float wt[8];
#pragma unroll
    for (int u = 0; u < 8; ++u) wt[u] = __expf(lrelu02(vv[u] + ald));
#pragma unroll
    for (int u = 0; u < 8; ++u) {
      den += wt[u];
      a0 += wt[u] * bf2f(hh[u].x);
      a1 += wt[u] * bf2f(hh[u].y);
      a2 += wt[u] * bf2f(hh[u].z);
      a3 += wt[u] * bf2f(hh[u].w);
    }
  }
  for (; s + 4 <= s1; s += 4) {
    int i0 = adj[s + 0], i1 = adj[s + 1], i2 = adj[s + 2], i3 = adj[s + 3];
    float v0 = alS[i0 * 4 + head];
    float v1 = alS[i1 * 4 + head];
    float v2 = alS[i2 * 4 + head];
    float v3 = alS[i3 * 4 + head];
    ushort4 h0 = *reinterpret_cast<const ushort4*>(hW + (size_t)i0 * 256 + c);
    ushort4 h1 = *reinterpret_cast<const ushort4*>(hW + (size_t)i1 * 256 + c);
    ushort4 h2 = *reinterpret_cast<const ushort4*>(hW + (size_t)i2 * 256 + c);
    ushort4 h3 = *reinterpret_cast<const ushort4*>(hW + (size_t)i3 * 256 + c);
    float w0 = __expf(lrelu02(v0 + ald));
    float w1 = __expf(lrelu02(v1 + ald));
    float w2 = __expf(lrelu02(v2 + ald));
    float w3 = __expf(lrelu02(v3 + ald));
    den += (w0 + w1) + (w2 + w3);
    a0 += w0 * bf2f(h0.x) + w1 * bf2f(h1.x) + w2 * bf2f(h2.x) + w3 * bf2f(h3.x);
    a1 += w0 * bf2f(h0.y) + w1 * bf2f(h1.y) + w2 * bf2f(h2.y) + w3 * bf2f(h3.y);
    a2 += w0 * bf2f(h0.z) + w1 * bf2f(h1.z) + w2 * bf2f(h2.z) + w3 * bf2f(h3.z);
    a3 += w0 * bf2f(h0.w) + w1 * bf2f(h1.w) + w2 * bf2f(h2.w) + w3 * bf2f(h3.w);
  }
  for (; s < s1; ++s) {
    int i0 = adj[s];
    float v0 = alS[i0 * 4 + head];
    ushort4 h0 = *reinterpret_cast<const ushort4*>(hW + (size_t)i0 * 256 + c);
    float w0 = __expf(lrelu02(v0 + ald));
    den += w0;
    a0 += w0 * bf2f(h0.x);
    a1 += w0 * bf2f(h0.y);
    a2 += w0 * bf2f(h0.z);
    a3 += w0 * bf2f(h0.w);
  }
  float inv = 1.f / (den + 1e-16f);
  float o0 = a0 * inv + bias[c + 0];
  float o1 = a1 * inv + bias[c + 1];
  float o2 = a2 * inv + bias[c + 2];
  float o3 = a3 * inv + bias[c + 3];
  if (RELU) {
    o0 = fmaxf(o0, 0.f); o1 = fmaxf(o1, 0.f);
    o2 = fmaxf(o2, 0.f); o3 = fmaxf(o3, 0.f);
  }
  ushort4 ov;
  ov.x = f2bf(o0); ov.y = f2bf(o1); ov.z = f2bf(o2); ov.w = f2bf(o3);
  *reinterpret_cast<ushort4*>(outb + (size_t)node * 256 + c) = ov;
}

// ---------------- GAT gather, 64 ch (1 head), bf16 in, fp32 out ------------
// wave per node; 4 groups of 16 lanes stride edges (4x unrolled).
template <bool RELU>
__global__ __launch_bounds__(256) void gat_gather64(const unsigned short* __restrict__ hW,
    const float* __restrict__ alS, const float* __restrict__ alD,
    const int* __restrict__ rowptr, const int* __restrict__ adj,
    const float* __restrict__ bias, float* __restrict__ out, int N) {
  int w = threadIdx.x >> 6, l = threadIdx.x & 63;
  int node = blockIdx.x * 4 + w;
  if (node >= N) return;
  int g = l >> 4;
  int c = (l & 15) << 2;
  float ald = alD[node];
  int s0 = rowptr[node], s1 = rowptr[node + 1];
  float den = 0.f, a0 = 0.f, a1 = 0.f, a2 = 0.f, a3 = 0.f;
  int s = s0 + g;
  for (; s + 12 < s1; s += 16) {
    int ix[4];
    ix[0] = adj[s]; ix[1] = adj[s + 4]; ix[2] = adj[s + 8]; ix[3] = adj[s + 12];
    float vv[4];
#pragma unroll
    for (int u = 0; u < 4; ++u) vv[u] = alS[ix[u]];
    ushort4 hh[4];
#pragma unroll
    for (int u = 0; u < 4; ++u)
      hh[u] = *reinterpret_cast<const ushort4*>(hW + (size_t)ix[u] * 64 + c);
#pragma unroll
    for (int u = 0; u < 4; ++u) {
      float wt = __expf(lrelu02(vv[u] + ald));
      den += wt;
      a0 += wt * bf2f(hh[u].x);
      a1 += wt * bf2f(hh[u].y);
      a2 += wt * bf2f(hh[u].z);
      a3 += wt * bf2f(hh[u].w);
    }
  }
  for (; s < s1; s += 4) {
    int i0 = adj[s];
    float v0 = alS[i0];
    ushort4 h0 = *reinterpret_cast<const ushort4*>(hW + (size_t)i0 * 64 + c);
    float w0 = __expf(lrelu02(v0 + ald));
    den += w0;
    a0 += w0 * bf2f(h0.x);
    a1 += w0 * bf2f(h0.y);
    a2 += w0 * bf2f(h0.z);
    a3 += w0 * bf2f(h0.w);
  }
#pragma unroll
  for (int off = 16; off <= 32; off <<= 1) {
    den += __shfl_xor(den, off);
    a0 += __shfl_xor(a0, off);
    a1 += __shfl_xor(a1, off);
    a2 += __shfl_xor(a2, off);
    a3 += __shfl_xor(a3, off);
  }
  if (g == 0) {
    float inv = 1.f / (den + 1e-16f);
    float o0 = a0 * inv + bias[c + 0];
    float o1 = a1 * inv + bias[c + 1];
    float o2 = a2 * inv + bias[c + 2];
    float o3 = a3 * inv + bias[c + 3];
    if (RELU) {
      o0 = fmaxf(o0, 0.f); o1 = fmaxf(o1, 0.f);
      o2 = fmaxf(o2, 0.f); o3 = fmaxf(o3, 0.f);
    }
    *reinterpret_cast<float4*>(out + (size_t)node * 64 + c) = make_float4(o0, o1, o2, o3);
  }
}

// ---------------------------------------------------------------------------
extern "C" void kernel_launch(void* const* d_in, const int* in_sizes, int n_in,
                              void* d_out, int out_size, void* d_ws, size_t ws_size,
                              hipStream_t stream) {
  const float* x      = (const float*)d_in[0];
  const float* W_rel  = (const float*)d_in[1];
  const float* b_rel  = (const float*)d_in[2];
  const float* W_root = (const float*)d_in[3];
  const float* W1     = (const float*)d_in[4];
  const float* a_s1   = (const float*)d_in[5];
  const float* a_d1   = (const float*)d_in[6];
  const float* b1     = (const float*)d_in[7];
  const float* W2     = (const float*)d_in[8];
  const float* a_s2   = (const float*)d_in[9];
  const float* a_d2   = (const float*)d_in[10];
  const float* b2     = (const float*)d_in[11];
  const float* W3     = (const float*)d_in[12];
  const float* a_s3   = (const float*)d_in[13];
  const float* a_d3   = (const float*)d_in[14];
  const float* b3     = (const float*)d_in[15];
  const int*   ei     = (const int*)d_in[16];

  int N = in_sizes[0] / 2;
  int E = in_sizes[16] / 2;
  const int* srcp = ei;
  const int* dstp = ei + E;
  int ESL = E + N;
  int nbk = (N + 255) >> 8;   // 196 buckets of 256 dst nodes

  // workspace layout (~79 MB), 16B-aligned sections
  unsigned short* h0b   = (unsigned short*)d_ws;           // N*64 bf16
  unsigned short* bufX  = h0b + (size_t)N * 64;            // N*256 bf16
  unsigned short* bufY  = bufX + (size_t)N * 256;          // N*256 bf16
  unsigned short* bufZ  = bufY + (size_t)N * 256;          // N*64 bf16
  unsigned short* Wt1   = bufZ + (size_t)N * 64;           // 256*64
  unsigned short* Wt2   = Wt1 + 256 * 64;                  // 256*256
  unsigned short* Wt3   = Wt2 + 256 * 256;                 // 64*256
  float* alS  = (float*)(Wt3 + 64 * 256);                  // N*4
  float* alD  = alS + (size_t)N * 4;                       // N*4
  uint32_t* pairs = (uint32_t*)(alD + (size_t)N * 4);      // ESL u32 packed
  int* adj    = (int*)(pairs + ESL);                       // ESL
  int* rowptr = adj + ESL;                                 // N+1
  int* bcount = rowptr + (N + 1);                          // 256
  int* boffs  = bcount + 256;                              // nbk+1
  int* gcursor= boffs + 257;                               // nbk

  int tb = 256;
  int nch = (ESL + CHUNK - 1) / CHUNK;
  int gN4 = (N + 3) / 4;

  // weight transpose/convert + bcount zeroing (single launch, runs first)
  wt3_kernel<<<(98304 + tb - 1) / tb, tb, 0, stream>>>(W1, Wt1, W2, Wt2, W3, Wt3, bcount);

  // bucket-local CSR build (shared by GraphConv + all 3 GAT layers)
  bcount_kernel<<<nch, tb, 0, stream>>>(dstp, E, N, nbk, bcount);
  bscan_kernel<<<1, 256, 0, stream>>>(bcount, nbk, boffs, gcursor, rowptr, N, ESL);
  bscatter_kernel<<<nch, tb, 0, stream>>>(srcp, dstp, E, N, nbk, gcursor, pairs);
  bcsr_kernel<<<nbk, tb, 0, stream>>>(pairs, boffs, nbk, N, rowptr, adj);

  // GraphConv via CSR gather (self-loop subtracted) + ReLU -> bf16
  graphconv_csr<<<gN4, 256, 0, stream>>>(x, rowptr, adj, W_rel, b_rel, W_root, h0b, N);

  dim3 gA(256 / 128, (N + 127) / 128);   // layers 1,2: N=256 -> 2 col tiles
  dim3 gB(1, (N + 255) / 256);           // layer 3: N=64

  // GAT layer 1: 64 -> 4x64, relu
  mfma_gemm<128, 128, 2, 2, 4><<<gA, 256, 0, stream>>>(h0b, Wt1, bufX, a_s1, a_d1, alS, alD, N, 256, 64);
  gat_gather256<true><<<gN4, 256, 0, stream>>>(bufX, alS, alD, rowptr, adj, b1, bufY, N);

  // GAT layer 2: 256 -> 4x64, relu
  mfma_gemm<128, 128, 2, 2, 4><<<gA, 256, 0, stream>>>(bufY, Wt2, bufX, a_s2, a_d2, alS, alD, N, 256, 256);
  gat_gather256<true><<<gN4, 256, 0, stream>>>(bufX, alS, alD, rowptr, adj, b2, bufY, N);

  // GAT layer 3: 256 -> 64, heads=1, no relu
  mfma_gemm<256, 64, 4, 1, 1><<<gB, 256, 0, stream>>>(bufY, Wt3, bufZ, a_s3, a_d3, alS, alD, N, 64, 256);
  gat_gather64<false><<<gN4, 256, 0, stream>>>(bufZ, alS, alD, rowptr, adj, b3, (float*)d_out, N);
}